// Round 4
// baseline (2232.184 us; speedup 1.0000x reference)
//
#include <hip/hip_runtime.h>
#include <stdint.h>

// FastRNN: B=64, T=512, I=256, H=512, fp32.
//   K1: wx = x @ W + bias  (bf16 MFMA GEMM) — unchanged from R3.
//   K2: h_t = sb*h + sa*tanh(wx_t + h @ U)
//       16 blocks = 4 batch-groups x 4 j-slices, U register-resident bf16
//       B-frags. R4: flag protocol replaced by SELF-VALIDATING TAGGED WORDS:
//       h published as fp32 with low 9 mantissa bits = step tag; consumers
//       poll the data itself (relaxed agent atomics, no fences, no flags,
//       no store-drain). Als double-buffered -> ONE barrier per step.

#define B_ 64
#define T_ 512
#define I_ 256
#define H_ 512
#define M_ (B_ * T_)  // 32768

#define WXB_BYTES ((size_t)M_ * H_ * 4)        // 64 MiB fp32
// Hbuf: fp32-tagged, double-buffered: 2*64*512*4 = 256 KiB

typedef short v8s __attribute__((ext_vector_type(8)));
typedef float v4f __attribute__((ext_vector_type(4)));
typedef unsigned long long u64t;

__device__ __forceinline__ uint16_t f2bf(float x) {
    union { float f; uint32_t u; } v; v.f = x;
    return (uint16_t)((v.u + 0x7FFFu + ((v.u >> 16) & 1u)) >> 16);
}

// --------------- K1: wxb[m][j] = x[m][:] @ W[:][j] + bias[j] ----------------
__global__ __launch_bounds__(256) void wx_gemm(
        const float* __restrict__ x, const float* __restrict__ W,
        const float* __restrict__ bias, float* __restrict__ wxb) {
    __shared__ uint16_t Asl[64][40];
    __shared__ uint16_t Bsl[4 * 64 * 8];

    const int tid = threadIdx.x;
    const int lane = tid & 63;
    const int w = tid >> 6;
    const int q = lane >> 4, c = lane & 15;
    const int mbase = (int)(blockIdx.x >> 3) * 64;
    const int nbase = (int)(blockIdx.x & 7) * 64;

    v4f acc[4];
    #pragma unroll
    for (int i = 0; i < 4; ++i) acc[i] = (v4f){0.f, 0.f, 0.f, 0.f};

    for (int ks = 0; ks < I_; ks += 32) {
        {
            int row = tid >> 2, c4 = tid & 3;
            const float* gp = x + (size_t)(mbase + row) * I_ + ks + c4 * 8;
            float4 f0 = *(const float4*)gp;
            float4 f1 = *(const float4*)(gp + 4);
            uint16_t* dp = &Asl[row][c4 * 8];
            dp[0] = f2bf(f0.x); dp[1] = f2bf(f0.y); dp[2] = f2bf(f0.z); dp[3] = f2bf(f0.w);
            dp[4] = f2bf(f1.x); dp[5] = f2bf(f1.y); dp[6] = f2bf(f1.z); dp[7] = f2bf(f1.w);
        }
        {
            int nt = tid >> 6;
            const float* gp = W + (size_t)(ks + q * 8) * H_ + nbase + nt * 16 + c;
            union { v8s v; uint16_t u[8]; } pk;
            #pragma unroll
            for (int jj = 0; jj < 8; ++jj) pk.u[jj] = f2bf(gp[(size_t)jj * H_]);
            *(v8s*)&Bsl[(nt * 64 + lane) * 8] = pk.v;
        }
        __syncthreads();
        const v8s* Bf = (const v8s*)Bsl;
        v8s a = *(const v8s*)&Asl[w * 16 + c][q * 8];
        #pragma unroll
        for (int nt = 0; nt < 4; ++nt) {
            v8s b = Bf[nt * 64 + lane];
            acc[nt] = __builtin_amdgcn_mfma_f32_16x16x32_bf16(a, b, acc[nt], 0, 0, 0);
        }
        __syncthreads();
    }
    #pragma unroll
    for (int nt = 0; nt < 4; ++nt) {
        int j = nbase + nt * 16 + c;
        float bj = bias[j];
        #pragma unroll
        for (int r = 0; r < 4; ++r) {
            int m = mbase + w * 16 + q * 4 + r;
            wxb[(size_t)m * H_ + j] = acc[nt][r] + bj;
        }
    }
}

// --------------- K2: recurrent scan ----------------------------------------
__global__ __launch_bounds__(256, 1) void rnn_scan(
        const float* __restrict__ U, const float* __restrict__ wxb,
        const float* __restrict__ alpha, const float* __restrict__ beta,
        float* __restrict__ out, uint32_t* __restrict__ Hbuf) {
    __shared__ uint16_t Als[2][16][520];   // double-buffered A staging, +8 pad

    const int bid = blockIdx.x;
    const int g = bid >> 2, s = bid & 3;
    const int tid = threadIdx.x;
    const int lane = tid & 63;
    const int w = tid >> 6;
    const int q = lane >> 4, c = lane & 15;
    const int row16 = tid >> 4, seg = tid & 15;

    float sa, sb;
    { float a = alpha[0], b = beta[0];
      sa = 1.f / (1.f + __expf(-a)); sb = 1.f / (1.f + __expf(-b)); }

    // Loop-invariant U B-frags: wave w owns ntiles 2w, 2w+1 of our 128-col slice.
    v8s Uf[2][16];
    #pragma unroll
    for (int nt = 0; nt < 2; ++nt) {
        int jg = s * 128 + (2 * w + nt) * 16 + c;
        #pragma unroll
        for (int kt = 0; kt < 16; ++kt) {
            const float* gp = U + (size_t)(kt * 32 + q * 8) * H_ + jg;
            union { v8s v; uint16_t u[8]; } pk;
            #pragma unroll
            for (int jj = 0; jj < 8; ++jj) pk.u[jj] = f2bf(gp[(size_t)jj * H_]);
            Uf[nt][kt] = pk.v;
        }
    }
    float hold[2][4];
    #pragma unroll
    for (int nt = 0; nt < 2; ++nt)
        #pragma unroll
        for (int r = 0; r < 4; ++r) hold[nt][r] = 0.f;

    for (int t = 0; t < T_; ++t) {
        const int p = t & 1;
        // ---- A: prefetch wx (nontemporal, overlaps the data poll) ----
        float wxv[2][4];
        #pragma unroll
        for (int nt = 0; nt < 2; ++nt) {
            int jg = s * 128 + (2 * w + nt) * 16 + c;
            #pragma unroll
            for (int r = 0; r < 4; ++r) {
                int bg = g * 16 + q * 4 + r;
                wxv[nt][r] = __builtin_nontemporal_load(
                    &wxb[((size_t)bg * T_ + t) * H_ + jg]);
            }
        }
        // ---- B: stage h_{t-1} into Als[p] via tagged-word polling ----
        if (t == 0) {
            uint4 z = {0, 0, 0, 0};
            uint4* dp = (uint4*)((uint16_t*)&Als[0][row16][0] + seg * 32);
            dp[0] = z; dp[1] = z; dp[2] = z; dp[3] = z;
        } else {
            const uint32_t etag = (uint32_t)(t & 511);
            const u64t* gp = (const u64t*)(Hbuf +
                ((size_t)p * B_ + g * 16 + row16) * H_ + seg * 32);
            u64t v[16];
            #pragma unroll
            for (int u2 = 0; u2 < 16; ++u2)
                v[u2] = __hip_atomic_load(&gp[u2], __ATOMIC_RELAXED,
                                          __HIP_MEMORY_SCOPE_AGENT);
            for (int guard = 0; guard < (1 << 16); ++guard) {
                uint32_t bad = 0;
                #pragma unroll
                for (int u2 = 0; u2 < 16; ++u2) {
                    uint32_t lo = (uint32_t)v[u2], hi = (uint32_t)(v[u2] >> 32);
                    bad |= ((lo ^ etag) | (hi ^ etag)) & 0x1FFu;
                }
                if (!bad) break;
                #pragma unroll
                for (int u2 = 0; u2 < 16; ++u2)   // batch reload: 1 RT per spin
                    v[u2] = __hip_atomic_load(&gp[u2], __ATOMIC_RELAXED,
                                              __HIP_MEMORY_SCOPE_AGENT);
            }
            uint32_t pk[16];
            #pragma unroll
            for (int u2 = 0; u2 < 16; ++u2) {
                uint32_t lo = (uint32_t)v[u2], hi = (uint32_t)(v[u2] >> 32);
                uint32_t b0 = (lo + 0x7FFFu + ((lo >> 16) & 1u)) >> 16;
                uint32_t b1 = (hi + 0x7FFFu + ((hi >> 16) & 1u)) >> 16;
                pk[u2] = b0 | (b1 << 16);
            }
            const uint4* sp = (const uint4*)pk;
            uint4* dp = (uint4*)((uint16_t*)&Als[p][row16][0] + seg * 32);
            dp[0] = sp[0]; dp[1] = sp[1]; dp[2] = sp[2]; dp[3] = sp[3];
        }
        __syncthreads();  // the ONLY barrier per step
        // ---- D: P = H @ U_slice ----
        v4f acc0 = (v4f){0.f, 0.f, 0.f, 0.f};
        v4f acc1 = (v4f){0.f, 0.f, 0.f, 0.f};
        #pragma unroll
        for (int kt = 0; kt < 16; ++kt) {
            v8s a = *(const v8s*)((const uint16_t*)&Als[p][c][0] + kt * 32 + q * 8);
            acc0 = __builtin_amdgcn_mfma_f32_16x16x32_bf16(a, Uf[0][kt], acc0, 0, 0, 0);
            acc1 = __builtin_amdgcn_mfma_f32_16x16x32_bf16(a, Uf[1][kt], acc1, 0, 0, 0);
        }
        // ---- E: epilogue; publish tagged h_new directly (no LDS hop) ----
        const uint32_t ptag = (uint32_t)((t + 1) & 511);
        #pragma unroll
        for (int nt = 0; nt < 2; ++nt) {
            v4f av = nt ? acc1 : acc0;
            int jg = s * 128 + (2 * w + nt) * 16 + c;
            #pragma unroll
            for (int r = 0; r < 4; ++r) {
                int bg = g * 16 + q * 4 + r;
                float pre = av[r] + wxv[nt][r];
                float ex = __expf(pre + pre);                          // e^{2x}
                float ct = 1.f - 2.f * __builtin_amdgcn_rcpf(ex + 1.f); // tanh
                float hn = sb * hold[nt][r] + sa * ct;
                hold[nt][r] = hn;
                union { float f; uint32_t u; } hb; hb.f = hn;
                uint32_t word = (hb.u & ~0x1FFu) | ptag;
                __hip_atomic_store(
                    &Hbuf[((size_t)(1 - p) * B_ + bg) * H_ + jg], word,
                    __ATOMIC_RELAXED, __HIP_MEMORY_SCOPE_AGENT);
            }
        }
        // ---- J: out stores (plain, ack at L2; off the sync path) ----
        #pragma unroll
        for (int nt = 0; nt < 2; ++nt) {
            int jg = s * 128 + (2 * w + nt) * 16 + c;
            #pragma unroll
            for (int r = 0; r < 4; ++r) {
                int bg = g * 16 + q * 4 + r;
                out[((size_t)bg * T_ + t) * H_ + jg] = hold[nt][r];
            }
        }
    }
}

extern "C" void kernel_launch(void* const* d_in, const int* in_sizes, int n_in,
                              void* d_out, int out_size, void* d_ws, size_t ws_size,
                              hipStream_t stream) {
    const float* x     = (const float*)d_in[0];
    const float* W     = (const float*)d_in[1];
    const float* U     = (const float*)d_in[2];
    const float* bias  = (const float*)d_in[3];
    const float* alpha = (const float*)d_in[4];
    const float* beta  = (const float*)d_in[5];
    float* out = (float*)d_out;

    char* ws = (char*)d_ws;
    float* wxb = (float*)ws;                                  // 64 MiB
    uint32_t* Hbuf = (uint32_t*)(ws + WXB_BYTES);             // 256 KiB tagged

    // No memset: tags self-validate (0xAA poison tag=170 never equals the
    // expected tags 1/2 on first reads), t==0 zero-fills Als directly.

    wx_gemm<<<dim3((M_ / 64) * (H_ / 64)), dim3(256), 0, stream>>>(x, W, bias, wxb);
    rnn_scan<<<dim3(16), dim3(256), 0, stream>>>(U, wxb, alpha, beta, out, Hbuf);
}

// Round 5
// 1424.174 us; speedup vs baseline: 1.5674x; 1.5674x over previous
//
#include <hip/hip_runtime.h>
#include <stdint.h>

// FastRNN: B=64, T=512, I=256, H=512, fp32.
//   K1: wx = x @ W + bias  (bf16 MFMA GEMM) — unchanged.
//   K2: h_t = sb*h + sa*tanh(wx_t + h @ U), 16 blocks = 4 batch-groups x
//       4 j-slices, U register-resident bf16 B-frags.
// R5: R3's packed-bf16 pipeline (producer LDS-pack -> 16B/thread u64 publish,
//     consumer raw copy) + SELF-VALIDATING TAG in every bf16 half's mantissa
//     LSB (tau = ((t+1)>>1)&1 distinguishes t from t-2 in same parity buf).
//     Deletes R3's drain-barrier + flag store + flag poll (2 RTs + barrier).
//     Tears harmless (per-16-bit tags). Memset Hbuf[0]=0x00 / Hbuf[1]=0xFF
//     makes warm-up reads tag-invalid for both first-use parities.

#define B_ 64
#define T_ 512
#define I_ 256
#define H_ 512
#define M_ (B_ * T_)  // 32768

#define WXB_BYTES  ((size_t)M_ * H_ * 4)       // 64 MiB fp32
#define HHALF_BYTES ((size_t)B_ * H_ * 2)      // 64 KiB bf16 per parity

typedef short v8s __attribute__((ext_vector_type(8)));
typedef float v4f __attribute__((ext_vector_type(4)));
typedef unsigned long long u64t;

__device__ __forceinline__ uint16_t f2bf(float x) {
    union { float f; uint32_t u; } v; v.f = x;
    return (uint16_t)((v.u + 0x7FFFu + ((v.u >> 16) & 1u)) >> 16);
}

// --------------- K1: wxb[m][j] = x[m][:] @ W[:][j] + bias[j] ----------------
__global__ __launch_bounds__(256) void wx_gemm(
        const float* __restrict__ x, const float* __restrict__ W,
        const float* __restrict__ bias, float* __restrict__ wxb) {
    __shared__ uint16_t Asl[64][40];
    __shared__ uint16_t Bsl[4 * 64 * 8];

    const int tid = threadIdx.x;
    const int lane = tid & 63;
    const int w = tid >> 6;
    const int q = lane >> 4, c = lane & 15;
    const int mbase = (int)(blockIdx.x >> 3) * 64;
    const int nbase = (int)(blockIdx.x & 7) * 64;

    v4f acc[4];
    #pragma unroll
    for (int i = 0; i < 4; ++i) acc[i] = (v4f){0.f, 0.f, 0.f, 0.f};

    for (int ks = 0; ks < I_; ks += 32) {
        {
            int row = tid >> 2, c4 = tid & 3;
            const float* gp = x + (size_t)(mbase + row) * I_ + ks + c4 * 8;
            float4 f0 = *(const float4*)gp;
            float4 f1 = *(const float4*)(gp + 4);
            uint16_t* dp = &Asl[row][c4 * 8];
            dp[0] = f2bf(f0.x); dp[1] = f2bf(f0.y); dp[2] = f2bf(f0.z); dp[3] = f2bf(f0.w);
            dp[4] = f2bf(f1.x); dp[5] = f2bf(f1.y); dp[6] = f2bf(f1.z); dp[7] = f2bf(f1.w);
        }
        {
            int nt = tid >> 6;
            const float* gp = W + (size_t)(ks + q * 8) * H_ + nbase + nt * 16 + c;
            union { v8s v; uint16_t u[8]; } pk;
            #pragma unroll
            for (int jj = 0; jj < 8; ++jj) pk.u[jj] = f2bf(gp[(size_t)jj * H_]);
            *(v8s*)&Bsl[(nt * 64 + lane) * 8] = pk.v;
        }
        __syncthreads();
        const v8s* Bf = (const v8s*)Bsl;
        v8s a = *(const v8s*)&Asl[w * 16 + c][q * 8];
        #pragma unroll
        for (int nt = 0; nt < 4; ++nt) {
            v8s b = Bf[nt * 64 + lane];
            acc[nt] = __builtin_amdgcn_mfma_f32_16x16x32_bf16(a, b, acc[nt], 0, 0, 0);
        }
        __syncthreads();
    }
    #pragma unroll
    for (int nt = 0; nt < 4; ++nt) {
        int j = nbase + nt * 16 + c;
        float bj = bias[j];
        #pragma unroll
        for (int r = 0; r < 4; ++r) {
            int m = mbase + w * 16 + q * 4 + r;
            wxb[(size_t)m * H_ + j] = acc[nt][r] + bj;
        }
    }
}

// --------------- K2: recurrent scan ----------------------------------------
__global__ __launch_bounds__(256, 1) void rnn_scan(
        const float* __restrict__ U, const float* __restrict__ wxb,
        const float* __restrict__ alpha, const float* __restrict__ beta,
        float* __restrict__ out, uint16_t* __restrict__ Hbuf) {
    __shared__ uint16_t Als[2][16][520];  // double-buffered A staging, +8 pad
    __shared__ uint16_t Hstg[16][128];    // this block's tagged h_new (bf16)

    const int bid = blockIdx.x;
    const int g = bid >> 2, s = bid & 3;
    const int tid = threadIdx.x;
    const int lane = tid & 63;
    const int w = tid >> 6;
    const int q = lane >> 4, c = lane & 15;
    const int row16 = tid >> 4, seg = tid & 15;

    float sa, sb;
    { float a = alpha[0], b = beta[0];
      sa = 1.f / (1.f + __expf(-a)); sb = 1.f / (1.f + __expf(-b)); }

    // Loop-invariant U B-frags: wave w owns ntiles 2w, 2w+1 of our 128-col slice.
    v8s Uf[2][16];
    #pragma unroll
    for (int nt = 0; nt < 2; ++nt) {
        int jg = s * 128 + (2 * w + nt) * 16 + c;
        #pragma unroll
        for (int kt = 0; kt < 16; ++kt) {
            const float* gp = U + (size_t)(kt * 32 + q * 8) * H_ + jg;
            union { v8s v; uint16_t u[8]; } pk;
            #pragma unroll
            for (int jj = 0; jj < 8; ++jj) pk.u[jj] = f2bf(gp[(size_t)jj * H_]);
            Uf[nt][kt] = pk.v;
        }
    }
    float hold[2][4];
    #pragma unroll
    for (int nt = 0; nt < 2; ++nt)
        #pragma unroll
        for (int r = 0; r < 4; ++r) hold[nt][r] = 0.f;

    for (int t = 0; t < T_; ++t) {
        const int p = t & 1;
        // ---- A: prefetch wx (nontemporal; overlaps the data poll) ----
        float wxv[2][4];
        #pragma unroll
        for (int nt = 0; nt < 2; ++nt) {
            int jg = s * 128 + (2 * w + nt) * 16 + c;
            #pragma unroll
            for (int r = 0; r < 4; ++r) {
                int bg = g * 16 + q * 4 + r;
                wxv[nt][r] = __builtin_nontemporal_load(
                    &wxb[((size_t)bg * T_ + t) * H_ + jg]);
            }
        }
        // ---- B: stage tagged h_{t-1} into Als[p]; poll = data itself ----
        if (t == 0) {
            uint4 z = {0, 0, 0, 0};
            uint4* dp = (uint4*)((uint16_t*)&Als[0][row16][0] + seg * 32);
            dp[0] = z; dp[1] = z; dp[2] = z; dp[3] = z;
        } else {
            const u64t tau64 = ((t >> 1) & 1) ? 0x0001000100010001ull : 0ull;
            const u64t lsb64 = 0x0001000100010001ull;
            const u64t* gp = (const u64t*)(Hbuf +
                ((size_t)p * B_ + g * 16 + row16) * H_ + seg * 32);
            u64t v[8];
            #pragma unroll
            for (int u2 = 0; u2 < 8; ++u2)
                v[u2] = __hip_atomic_load(&gp[u2], __ATOMIC_RELAXED,
                                          __HIP_MEMORY_SCOPE_AGENT);
            for (int guard = 0; guard < (1 << 20); ++guard) {
                u64t bad = 0;
                #pragma unroll
                for (int u2 = 0; u2 < 8; ++u2)
                    bad |= (v[u2] ^ tau64) & lsb64;
                if (!bad) break;
                #pragma unroll
                for (int u2 = 0; u2 < 8; ++u2)   // batch reload: 1 RT per spin
                    v[u2] = __hip_atomic_load(&gp[u2], __ATOMIC_RELAXED,
                                              __HIP_MEMORY_SCOPE_AGENT);
            }
            u64t* dp = (u64t*)((uint16_t*)&Als[p][row16][0] + seg * 32);
            #pragma unroll
            for (int u2 = 0; u2 < 8; ++u2) dp[u2] = v[u2];  // raw copy, no convert
        }
        __syncthreads();  // C
        // ---- D: P = H @ U_slice ----
        v4f acc0 = (v4f){0.f, 0.f, 0.f, 0.f};
        v4f acc1 = (v4f){0.f, 0.f, 0.f, 0.f};
        #pragma unroll
        for (int kt = 0; kt < 16; ++kt) {
            v8s a = *(const v8s*)((const uint16_t*)&Als[p][c][0] + kt * 32 + q * 8);
            acc0 = __builtin_amdgcn_mfma_f32_16x16x32_bf16(a, Uf[0][kt], acc0, 0, 0, 0);
            acc1 = __builtin_amdgcn_mfma_f32_16x16x32_bf16(a, Uf[1][kt], acc1, 0, 0, 0);
        }
        // ---- E: epilogue (fp32 state in regs); tagged bf16 -> Hstg ----
        const uint16_t tau = (uint16_t)(((t + 1) >> 1) & 1);
        #pragma unroll
        for (int nt = 0; nt < 2; ++nt) {
            v4f av = nt ? acc1 : acc0;
            int jl = (2 * w + nt) * 16 + c;
            #pragma unroll
            for (int r = 0; r < 4; ++r) {
                float pre = av[r] + wxv[nt][r];
                float ex = __expf(pre + pre);                           // e^{2x}
                float ct = 1.f - 2.f * __builtin_amdgcn_rcpf(ex + 1.f); // tanh
                float hn = sb * hold[nt][r] + sa * ct;
                hold[nt][r] = hn;
                Hstg[q * 4 + r][jl] = (uint16_t)((f2bf(hn) & 0xFFFEu) | tau);
            }
        }
        __syncthreads();  // F: Hstg complete
        // ---- G: publish packed 16 B/thread (relaxed agent atomics) ----
        {
            int i0 = tid * 2;
            #pragma unroll
            for (int k2 = 0; k2 < 2; ++k2) {
                int i = i0 + k2;
                int b = i >> 5, jo = (i & 31) * 4;
                u64t v = *(const u64t*)&Hstg[b][jo];
                u64t* pp = (u64t*)(Hbuf +
                    ((size_t)(1 - p) * B_ + g * 16 + b) * H_ + s * 128 + jo);
                __hip_atomic_store(pp, v, __ATOMIC_RELAXED,
                                   __HIP_MEMORY_SCOPE_AGENT);
            }
        }
        // ---- J: out stores (off the sync path; no drain, no flag) ----
        #pragma unroll
        for (int nt = 0; nt < 2; ++nt) {
            int jg = s * 128 + (2 * w + nt) * 16 + c;
            #pragma unroll
            for (int r = 0; r < 4; ++r) {
                int bg = g * 16 + q * 4 + r;
                __builtin_nontemporal_store(hold[nt][r],
                    &out[((size_t)bg * T_ + t) * H_ + jg]);
            }
        }
    }
}

extern "C" void kernel_launch(void* const* d_in, const int* in_sizes, int n_in,
                              void* d_out, int out_size, void* d_ws, size_t ws_size,
                              hipStream_t stream) {
    const float* x     = (const float*)d_in[0];
    const float* W     = (const float*)d_in[1];
    const float* U     = (const float*)d_in[2];
    const float* bias  = (const float*)d_in[3];
    const float* alpha = (const float*)d_in[4];
    const float* beta  = (const float*)d_in[5];
    float* out = (float*)d_out;

    char* ws = (char*)d_ws;
    float* wxb = (float*)ws;                                  // 64 MiB
    uint16_t* Hbuf = (uint16_t*)(ws + WXB_BYTES);             // 128 KiB tagged bf16

    // Warm-up tag safety: parity 0 halves get LSB=0 (invalid at t'=2 which
    // expects tau=1), parity 1 halves get LSB=1 (invalid at t'=1, tau=0).
    hipMemsetAsync(Hbuf, 0x00, HHALF_BYTES, stream);
    hipMemsetAsync((char*)Hbuf + HHALF_BYTES, 0xFF, HHALF_BYTES, stream);

    wx_gemm<<<dim3((M_ / 64) * (H_ / 64)), dim3(256), 0, stream>>>(x, W, bias, wxb);
    rnn_scan<<<dim3(16), dim3(256), 0, stream>>>(U, wxb, alpha, beta, out, Hbuf);
}

// Round 6
// 1405.715 us; speedup vs baseline: 1.5879x; 1.0131x over previous
//
#include <hip/hip_runtime.h>
#include <stdint.h>

// FastRNN: B=64, T=512, I=256, H=512, fp32.
//   K1: wx = x @ W + bias  (bf16 MFMA GEMM) — unchanged.
//   K2: h_t = sb*h + sa*tanh(wx_t + h @ U), 16 blocks = 4 batch-groups x
//       4 j-slices, U register-resident bf16 B-frags, self-validating
//       tagged-bf16 h exchange (tag in each half's mantissa LSB).
// R6 (surgical, 2 changes): the poll's s_waitcnt vmcnt(0) is a FIFO wait —
//   it was serialized behind our OWN slow VMEM:
//   (1) out stores: nontemporal (retire at HBM ~900cy) -> PLAIN stores
//       (retire in local L2 ~200cy; background writeback).
//   (2) wx loads: issued at poll time (HBM ~900cy in the poll wait) ->
//       software-pipelined one step ahead (issued right after barrier C,
//       ~1500cy before the poll that would wait on them).

#define B_ 64
#define T_ 512
#define I_ 256
#define H_ 512
#define M_ (B_ * T_)  // 32768

#define WXB_BYTES  ((size_t)M_ * H_ * 4)       // 64 MiB fp32
#define HHALF_BYTES ((size_t)B_ * H_ * 2)      // 64 KiB bf16 per parity

typedef short v8s __attribute__((ext_vector_type(8)));
typedef float v4f __attribute__((ext_vector_type(4)));
typedef unsigned long long u64t;

__device__ __forceinline__ uint16_t f2bf(float x) {
    union { float f; uint32_t u; } v; v.f = x;
    return (uint16_t)((v.u + 0x7FFFu + ((v.u >> 16) & 1u)) >> 16);
}

// --------------- K1: wxb[m][j] = x[m][:] @ W[:][j] + bias[j] ----------------
__global__ __launch_bounds__(256) void wx_gemm(
        const float* __restrict__ x, const float* __restrict__ W,
        const float* __restrict__ bias, float* __restrict__ wxb) {
    __shared__ uint16_t Asl[64][40];
    __shared__ uint16_t Bsl[4 * 64 * 8];

    const int tid = threadIdx.x;
    const int lane = tid & 63;
    const int w = tid >> 6;
    const int q = lane >> 4, c = lane & 15;
    const int mbase = (int)(blockIdx.x >> 3) * 64;
    const int nbase = (int)(blockIdx.x & 7) * 64;

    v4f acc[4];
    #pragma unroll
    for (int i = 0; i < 4; ++i) acc[i] = (v4f){0.f, 0.f, 0.f, 0.f};

    for (int ks = 0; ks < I_; ks += 32) {
        {
            int row = tid >> 2, c4 = tid & 3;
            const float* gp = x + (size_t)(mbase + row) * I_ + ks + c4 * 8;
            float4 f0 = *(const float4*)gp;
            float4 f1 = *(const float4*)(gp + 4);
            uint16_t* dp = &Asl[row][c4 * 8];
            dp[0] = f2bf(f0.x); dp[1] = f2bf(f0.y); dp[2] = f2bf(f0.z); dp[3] = f2bf(f0.w);
            dp[4] = f2bf(f1.x); dp[5] = f2bf(f1.y); dp[6] = f2bf(f1.z); dp[7] = f2bf(f1.w);
        }
        {
            int nt = tid >> 6;
            const float* gp = W + (size_t)(ks + q * 8) * H_ + nbase + nt * 16 + c;
            union { v8s v; uint16_t u[8]; } pk;
            #pragma unroll
            for (int jj = 0; jj < 8; ++jj) pk.u[jj] = f2bf(gp[(size_t)jj * H_]);
            *(v8s*)&Bsl[(nt * 64 + lane) * 8] = pk.v;
        }
        __syncthreads();
        const v8s* Bf = (const v8s*)Bsl;
        v8s a = *(const v8s*)&Asl[w * 16 + c][q * 8];
        #pragma unroll
        for (int nt = 0; nt < 4; ++nt) {
            v8s b = Bf[nt * 64 + lane];
            acc[nt] = __builtin_amdgcn_mfma_f32_16x16x32_bf16(a, b, acc[nt], 0, 0, 0);
        }
        __syncthreads();
    }
    #pragma unroll
    for (int nt = 0; nt < 4; ++nt) {
        int j = nbase + nt * 16 + c;
        float bj = bias[j];
        #pragma unroll
        for (int r = 0; r < 4; ++r) {
            int m = mbase + w * 16 + q * 4 + r;
            wxb[(size_t)m * H_ + j] = acc[nt][r] + bj;
        }
    }
}

// --------------- K2: recurrent scan ----------------------------------------
__global__ __launch_bounds__(256, 1) void rnn_scan(
        const float* __restrict__ U, const float* __restrict__ wxb,
        const float* __restrict__ alpha, const float* __restrict__ beta,
        float* __restrict__ out, uint16_t* __restrict__ Hbuf) {
    __shared__ uint16_t Als[2][16][520];  // double-buffered A staging, +8 pad
    __shared__ uint16_t Hstg[16][128];    // this block's tagged h_new (bf16)

    const int bid = blockIdx.x;
    const int g = bid >> 2, s = bid & 3;
    const int tid = threadIdx.x;
    const int lane = tid & 63;
    const int w = tid >> 6;
    const int q = lane >> 4, c = lane & 15;
    const int row16 = tid >> 4, seg = tid & 15;

    float sa, sb;
    { float a = alpha[0], b = beta[0];
      sa = 1.f / (1.f + __expf(-a)); sb = 1.f / (1.f + __expf(-b)); }

    // Loop-invariant U B-frags: wave w owns ntiles 2w, 2w+1 of our 128-col slice.
    v8s Uf[2][16];
    #pragma unroll
    for (int nt = 0; nt < 2; ++nt) {
        int jg = s * 128 + (2 * w + nt) * 16 + c;
        #pragma unroll
        for (int kt = 0; kt < 16; ++kt) {
            const float* gp = U + (size_t)(kt * 32 + q * 8) * H_ + jg;
            union { v8s v; uint16_t u[8]; } pk;
            #pragma unroll
            for (int jj = 0; jj < 8; ++jj) pk.u[jj] = f2bf(gp[(size_t)jj * H_]);
            Uf[nt][kt] = pk.v;
        }
    }
    float hold[2][4];
    #pragma unroll
    for (int nt = 0; nt < 2; ++nt)
        #pragma unroll
        for (int r = 0; r < 4; ++r) hold[nt][r] = 0.f;

    // wx prefetch: one step ahead (loads issued ~1 step before consumption,
    // so the poll's vmcnt FIFO never contains fresh HBM loads).
    float wxv[2][4], wxn[2][4];
    #pragma unroll
    for (int nt = 0; nt < 2; ++nt) {
        int jg = s * 128 + (2 * w + nt) * 16 + c;
        #pragma unroll
        for (int r = 0; r < 4; ++r) {
            int bg = g * 16 + q * 4 + r;
            wxn[nt][r] = __builtin_nontemporal_load(
                &wxb[((size_t)bg * T_ + 0) * H_ + jg]);
        }
    }

    for (int t = 0; t < T_; ++t) {
        const int p = t & 1;
        // rotate prefetch buffer (loads are ~1 step old -> retired, no stall)
        #pragma unroll
        for (int nt = 0; nt < 2; ++nt)
            #pragma unroll
            for (int r = 0; r < 4; ++r) wxv[nt][r] = wxn[nt][r];
        // ---- B: stage tagged h_{t-1} into Als[p]; poll = data itself ----
        if (t == 0) {
            uint4 z = {0, 0, 0, 0};
            uint4* dp = (uint4*)((uint16_t*)&Als[0][row16][0] + seg * 32);
            dp[0] = z; dp[1] = z; dp[2] = z; dp[3] = z;
        } else {
            const u64t tau64 = ((t >> 1) & 1) ? 0x0001000100010001ull : 0ull;
            const u64t lsb64 = 0x0001000100010001ull;
            const u64t* gp = (const u64t*)(Hbuf +
                ((size_t)p * B_ + g * 16 + row16) * H_ + seg * 32);
            u64t v[8];
            #pragma unroll
            for (int u2 = 0; u2 < 8; ++u2)
                v[u2] = __hip_atomic_load(&gp[u2], __ATOMIC_RELAXED,
                                          __HIP_MEMORY_SCOPE_AGENT);
            for (int guard = 0; guard < (1 << 20); ++guard) {
                u64t bad = 0;
                #pragma unroll
                for (int u2 = 0; u2 < 8; ++u2)
                    bad |= (v[u2] ^ tau64) & lsb64;
                if (!bad) break;
                #pragma unroll
                for (int u2 = 0; u2 < 8; ++u2)   // batch reload: 1 RT per spin
                    v[u2] = __hip_atomic_load(&gp[u2], __ATOMIC_RELAXED,
                                              __HIP_MEMORY_SCOPE_AGENT);
            }
            u64t* dp = (u64t*)((uint16_t*)&Als[p][row16][0] + seg * 32);
            #pragma unroll
            for (int u2 = 0; u2 < 8; ++u2) dp[u2] = v[u2];  // raw copy
        }
        __syncthreads();  // C
        // ---- prefetch wx for t+1 (max distance from the next poll) ----
        if (t + 1 < T_) {
            #pragma unroll
            for (int nt = 0; nt < 2; ++nt) {
                int jg = s * 128 + (2 * w + nt) * 16 + c;
                #pragma unroll
                for (int r = 0; r < 4; ++r) {
                    int bg = g * 16 + q * 4 + r;
                    wxn[nt][r] = __builtin_nontemporal_load(
                        &wxb[((size_t)bg * T_ + (t + 1)) * H_ + jg]);
                }
            }
        }
        // ---- D: P = H @ U_slice ----
        v4f acc0 = (v4f){0.f, 0.f, 0.f, 0.f};
        v4f acc1 = (v4f){0.f, 0.f, 0.f, 0.f};
        #pragma unroll
        for (int kt = 0; kt < 16; ++kt) {
            v8s a = *(const v8s*)((const uint16_t*)&Als[p][c][0] + kt * 32 + q * 8);
            acc0 = __builtin_amdgcn_mfma_f32_16x16x32_bf16(a, Uf[0][kt], acc0, 0, 0, 0);
            acc1 = __builtin_amdgcn_mfma_f32_16x16x32_bf16(a, Uf[1][kt], acc1, 0, 0, 0);
        }
        // ---- E: epilogue (fp32 state in regs); tagged bf16 -> Hstg ----
        const uint16_t tau = (uint16_t)(((t + 1) >> 1) & 1);
        #pragma unroll
        for (int nt = 0; nt < 2; ++nt) {
            v4f av = nt ? acc1 : acc0;
            int jl = (2 * w + nt) * 16 + c;
            #pragma unroll
            for (int r = 0; r < 4; ++r) {
                float pre = av[r] + wxv[nt][r];
                float ex = __expf(pre + pre);                           // e^{2x}
                float ct = 1.f - 2.f * __builtin_amdgcn_rcpf(ex + 1.f); // tanh
                float hn = sb * hold[nt][r] + sa * ct;
                hold[nt][r] = hn;
                Hstg[q * 4 + r][jl] = (uint16_t)((f2bf(hn) & 0xFFFEu) | tau);
            }
        }
        __syncthreads();  // F: Hstg complete
        // ---- G: publish packed 16 B/thread (relaxed agent atomics) ----
        {
            int i0 = tid * 2;
            #pragma unroll
            for (int k2 = 0; k2 < 2; ++k2) {
                int i = i0 + k2;
                int b = i >> 5, jo = (i & 31) * 4;
                u64t v = *(const u64t*)&Hstg[b][jo];
                u64t* pp = (u64t*)(Hbuf +
                    ((size_t)(1 - p) * B_ + g * 16 + b) * H_ + s * 128 + jo);
                __hip_atomic_store(pp, v, __ATOMIC_RELAXED,
                                   __HIP_MEMORY_SCOPE_AGENT);
            }
        }
        // ---- J: out stores — PLAIN (retire in local L2, not at HBM) ----
        #pragma unroll
        for (int nt = 0; nt < 2; ++nt) {
            int jg = s * 128 + (2 * w + nt) * 16 + c;
            #pragma unroll
            for (int r = 0; r < 4; ++r) {
                int bg = g * 16 + q * 4 + r;
                out[((size_t)bg * T_ + t) * H_ + jg] = hold[nt][r];
            }
        }
    }
}

extern "C" void kernel_launch(void* const* d_in, const int* in_sizes, int n_in,
                              void* d_out, int out_size, void* d_ws, size_t ws_size,
                              hipStream_t stream) {
    const float* x     = (const float*)d_in[0];
    const float* W     = (const float*)d_in[1];
    const float* U     = (const float*)d_in[2];
    const float* bias  = (const float*)d_in[3];
    const float* alpha = (const float*)d_in[4];
    const float* beta  = (const float*)d_in[5];
    float* out = (float*)d_out;

    char* ws = (char*)d_ws;
    float* wxb = (float*)ws;                                  // 64 MiB
    uint16_t* Hbuf = (uint16_t*)(ws + WXB_BYTES);             // 128 KiB tagged bf16

    // Warm-up tag safety: parity 0 halves get LSB=0 (invalid at t'=2 which
    // expects tau=1), parity 1 halves get LSB=1 (invalid at t'=1, tau=0).
    hipMemsetAsync(Hbuf, 0x00, HHALF_BYTES, stream);
    hipMemsetAsync((char*)Hbuf + HHALF_BYTES, 0xFF, HHALF_BYTES, stream);

    wx_gemm<<<dim3((M_ / 64) * (H_ / 64)), dim3(256), 0, stream>>>(x, W, bias, wxb);
    rnn_scan<<<dim3(16), dim3(256), 0, stream>>>(U, wxb, alpha, beta, out, Hbuf);
}